// Round 3
// baseline (341.853 us; speedup 1.0000x reference)
//
#include <hip/hip_runtime.h>
#include <stdint.h>

typedef __attribute__((ext_vector_type(8))) short bf16x8;
typedef __attribute__((ext_vector_type(4))) float f32x4;

// ---- LDS layout (bytes), total 53328 -> 3 blocks/CU (159984 <= 163840) ----
#define OFF_ACT  0        // [256][64] bf16, stride 128B, swz off128()  (h / cin / c1 / c2)
#define OFF_W0   32768    // [64][32] bf16, stride 64B, swz ^(((row>>1)&3)<<4)
#define OFF_WC0  36864    // [64][32] bf16 (col31 zero-pad), same swizzle
#define OFF_WC1  40960    // [64][64] bf16, stride 128B, swz off128()
#define OFF_OUT4 49152    // [256][4] f32  (sigma, r, g, b)
#define OFF_SHB  53248    // [2][16] u16 (bf16 SH coeffs)
#define OFF_WTOT 53312    // [4] int
#define SMEM_BYTES 53328

__device__ __forceinline__ unsigned short f2bf(float f) {
    unsigned int u = __float_as_uint(f);
    unsigned int r = (u + 0x7FFFu + ((u >> 16) & 1u)) >> 16;   // RNE
    return (unsigned short)r;
}

__device__ __forceinline__ bf16x8 pack8(float4 a, float4 b) {
    bf16x8 r;
    r[0] = (short)f2bf(a.x); r[1] = (short)f2bf(a.y);
    r[2] = (short)f2bf(a.z); r[3] = (short)f2bf(a.w);
    r[4] = (short)f2bf(b.x); r[5] = (short)f2bf(b.y);
    r[6] = (short)f2bf(b.z); r[7] = (short)f2bf(b.w);
    return r;
}

// 128B-stride tiles (ACT/WC1): slot = (row&7) ^ (bit3(row)<<1)
//  - b128 reads (rows 0..15, fixed col): each 16B slot covered exactly 2x -> free
//  - b16 D-writes (rows r,r+4,r+8,r+12): 4 distinct slots -> conflict-free
__device__ __forceinline__ int off128(int row, int col) {
    int off = row * 128 + col * 2;
    return off ^ ((((row & 7) ^ ((row >> 2) & 2))) << 4);
}
// 64B-stride tiles (W0/WC0): swizzle ^(((row>>1)&3)<<4)  -> <=2-way (free)
__device__ __forceinline__ bf16x8 ldf32(const char* base, int row, int k0) {
    int off = row * 64 + k0 * 2;
    off ^= ((row >> 1) & 3) << 4;
    return *(const bf16x8*)(base + off);
}
__device__ __forceinline__ bf16x8 ldf64(const char* base, int row, int k0) {
    return *(const bf16x8*)(base + off128(row, k0));
}

// Probe: is mask stored as int32 (1 word/elem) or raw bool bytes?
// Ray 0 has exactly 128 valid samples -> sum of first 512 i32 words == 128 iff i32.
__global__ void __launch_bounds__(64) detect_mask_kernel(const int* __restrict__ m, int* __restrict__ flag) {
    int l = threadIdx.x;
    unsigned long long s = 0;
    #pragma unroll
    for (int i = 0; i < 8; ++i) s += (unsigned long long)(unsigned int)m[l + i * 64];
    #pragma unroll
    for (int d = 32; d >= 1; d >>= 1) s += __shfl_down(s, d, 64);
    if (l == 0) *flag = (s == 128ull) ? 1 : 0;
}

__global__ void __launch_bounds__(256, 3) nnrender_main(
    const float* __restrict__ df, const void* __restrict__ maskp, const float* __restrict__ rays,
    const float* __restrict__ Ws0, const float* __restrict__ Ws1, const float* __restrict__ Wc0,
    const float* __restrict__ Wc1, const float* __restrict__ Wc2,
    float* __restrict__ out, const int* __restrict__ flagp) {

    __shared__ __align__(16) char smem[SMEM_BYTES];
    const int tid = threadIdx.x;
    const int w = tid >> 6;           // wave 0..3, owns rows [64w, 64w+64)
    const int l = tid & 63;
    const int q = l & 15;             // fragment row/col-within-16
    const int h8 = (l >> 4) << 3;     // k-chunk base
    const int h4 = (l >> 4) << 2;     // D row base
    const int blk = blockIdx.x;
    const int b0 = blk * 2;

    char* ACT = smem + OFF_ACT;
    const int use_i32 = *flagp;

    // ---- phase 0: df A-frags + W1/WC2 B-frags from global; stage W0/WC0/WC1; SH; mask scan ----
    float4 dfa[4], dfb[4];
    {
        const float* p0 = df + ((size_t)(blk * 256 + w * 64 + q)) * 32 + h8;
        #pragma unroll
        for (int m = 0; m < 4; ++m) {
            const float* p = p0 + m * 16 * 32;
            dfa[m] = *(const float4*)p;
            dfb[m] = *(const float4*)(p + 4);
        }
    }
    float4 w1v[4], w2v[4];
    {
        const float* p1 = Ws1 + q * 64 + h8;
        w1v[0] = *(const float4*)p1;        w1v[1] = *(const float4*)(p1 + 4);
        w1v[2] = *(const float4*)(p1 + 32); w1v[3] = *(const float4*)(p1 + 36);
        int qc = (q < 3) ? q : 0;           // rows 3..15 unused (D cols >=3 ignored)
        const float* p2 = Wc2 + qc * 64 + h8;
        w2v[0] = *(const float4*)p2;        w2v[1] = *(const float4*)(p2 + 4);
        w2v[2] = *(const float4*)(p2 + 32); w2v[3] = *(const float4*)(p2 + 36);
    }

    // mask load: thread covers 4 consecutive slots; waves 0,1 -> ray b0; 2,3 -> ray b0+1
    unsigned int mb[4];
    {
        size_t base = (size_t)b0 * 512 + tid * 4;
        if (use_i32) {
            int4 mv = *(const int4*)((const int*)maskp + base);
            mb[0] = mv.x != 0; mb[1] = mv.y != 0; mb[2] = mv.z != 0; mb[3] = mv.w != 0;
        } else {
            unsigned int u = *(const unsigned int*)((const unsigned char*)maskp + base);
            mb[0] = (u & 0xFFu) != 0; mb[1] = ((u >> 8) & 0xFFu) != 0;
            mb[2] = ((u >> 16) & 0xFFu) != 0; mb[3] = (u >> 24) != 0;
        }
    }

    // stage W0 / WC0 (scalar, 64B-stride swizzle)
    for (int i = tid; i < 2048; i += 256) {
        int n = i >> 5, k = i & 31;
        int off = i * 2 ^ (((n >> 1) & 3) << 4);
        *(unsigned short*)(smem + OFF_W0 + off) = f2bf(Ws0[n * 32 + k]);
        float v = (k < 31) ? Wc0[n * 31 + k] : 0.f;
        *(unsigned short*)(smem + OFF_WC0 + off) = f2bf(v);
    }
    // stage WC1 (vectorized float4 -> packed 4x bf16 u64 store)
    #pragma unroll
    for (int it = 0; it < 4; ++it) {
        int idx = (tid + it * 256) * 4;          // element index, k multiple of 4
        int n = idx >> 6, k = idx & 63;
        float4 v = *(const float4*)(Wc1 + n * 64 + k);
        unsigned long long pk = (unsigned long long)f2bf(v.x)
                              | ((unsigned long long)f2bf(v.y) << 16)
                              | ((unsigned long long)f2bf(v.z) << 32)
                              | ((unsigned long long)f2bf(v.w) << 48);
        *(unsigned long long*)(smem + OFF_WC1 + off128(n, k)) = pk;
    }

    if (tid < 2) {  // SH deg-4 (16 coeffs) for this block's 2 rays
        const float* rd = rays + (size_t)(b0 + tid) * 3;
        float x = rd[0], y = rd[1], z = rd[2];
        float x2 = x * x, y2 = y * y, z2 = z * z, xy = x * y, yz = y * z, xz = x * z;
        float s[16];
        s[0] = 0.28209479177387814f;
        s[1] = -0.48860251190291987f * y;
        s[2] =  0.48860251190291987f * z;
        s[3] = -0.48860251190291987f * x;
        s[4] =  1.0925484305920792f * xy;
        s[5] = -1.0925484305920792f * yz;
        s[6] =  0.94617469575755997f * z2 - 0.31539156525251999f;
        s[7] = -1.0925484305920792f * xz;
        s[8] =  0.54627421529603959f * (x2 - y2);
        s[9] =  0.59004358992664352f * y * (-3.0f * x2 + y2);
        s[10] = 2.8906114426405538f * xy * z;
        s[11] = 0.45704579946446572f * y * (1.0f - 5.0f * z2);
        s[12] = 0.3731763325901154f * z * (5.0f * z2 - 3.0f);
        s[13] = 0.45704579946446572f * x * (1.0f - 5.0f * z2);
        s[14] = 1.445305721320277f * z * (x2 - y2);
        s[15] = 0.59004358992664352f * x * (-x2 + 3.0f * y2);
        unsigned short* d = (unsigned short*)(smem + OFF_SHB) + tid * 16;
        #pragma unroll
        for (int i = 0; i < 16; ++i) d[i] = f2bf(s[i]);
    }

    // wave-wide inclusive scan of per-thread valid count
    int c = (int)(mb[0] + mb[1] + mb[2] + mb[3]);
    int incl = c;
    #pragma unroll
    for (int d = 1; d < 64; d <<= 1) {
        int v = __shfl_up(incl, d, 64);
        if (l >= d) incl += v;
    }
    if (l == 63) ((int*)(smem + OFF_WTOT))[w] = incl;

    // convert df to bf16 fragments (VALU, overlaps staging latency)
    bf16x8 dfr[4];
    #pragma unroll
    for (int m = 0; m < 4; ++m) dfr[m] = pack8(dfa[m], dfb[m]);
    bf16x8 bW1[2], bW2[2];
    bW1[0] = pack8(w1v[0], w1v[1]); bW1[1] = pack8(w1v[2], w1v[3]);
    bW2[0] = pack8(w2v[0], w2v[1]); bW2[1] = pack8(w2v[2], w2v[3]);

    __syncthreads();   // ---- barrier 1 ----

    // finalize ranks (within-ray, kept in registers until epilogue)
    int rank0;
    {
        int base = (w & 1) ? ((int*)(smem + OFF_WTOT))[w - 1] : 0;
        rank0 = base + incl - c;
    }

    // ---- GEMM1: h = relu(df @ Ws0^T)  [256,32]x[32,64] -> ACT ----
    #pragma unroll
    for (int n = 0; n < 4; ++n) {
        bf16x8 b = ldf32(smem + OFF_W0, n * 16 + q, h8);
        #pragma unroll
        for (int m = 0; m < 4; ++m) {
            f32x4 acc = {0.f, 0.f, 0.f, 0.f};
            acc = __builtin_amdgcn_mfma_f32_16x16x32_bf16(dfr[m], b, acc, 0, 0, 0);
            #pragma unroll
            for (int r = 0; r < 4; ++r) {
                int row = w * 64 + m * 16 + h4 + r;
                *(unsigned short*)(ACT + off128(row, n * 16 + q)) = f2bf(fmaxf(acc[r], 0.f));
            }
        }
    }

    // ---- GEMM2: dc = h @ Ws1^T; sigma=relu(dc0)->OUT4; dc[1:16]->cin cols16..30; SH->cols0..15 ----
    {
        bf16x8 a2[4][2];
        #pragma unroll
        for (int m = 0; m < 4; ++m)
            #pragma unroll
            for (int kk = 0; kk < 2; ++kk)
                a2[m][kk] = ldf64(ACT, w * 64 + m * 16 + q, kk * 32 + h8);
        asm volatile("s_waitcnt lgkmcnt(0)" ::: "memory");
        __builtin_amdgcn_sched_barrier(0);
        {   // overwrite cin cols 0..15 with SH of this wave's ray (own row per lane)
            int rayloc = w >> 1;
            bf16x8 shlo = *(const bf16x8*)(smem + OFF_SHB + rayloc * 32);
            bf16x8 shhi = *(const bf16x8*)(smem + OFF_SHB + rayloc * 32 + 16);
            int row = w * 64 + l;
            *(bf16x8*)(ACT + off128(row, 0)) = shlo;
            *(bf16x8*)(ACT + off128(row, 8)) = shhi;
        }
        #pragma unroll
        for (int m = 0; m < 4; ++m) {
            f32x4 acc = {0.f, 0.f, 0.f, 0.f};
            acc = __builtin_amdgcn_mfma_f32_16x16x32_bf16(a2[m][0], bW1[0], acc, 0, 0, 0);
            acc = __builtin_amdgcn_mfma_f32_16x16x32_bf16(a2[m][1], bW1[1], acc, 0, 0, 0);
            #pragma unroll
            for (int r = 0; r < 4; ++r) {
                int row = w * 64 + m * 16 + h4 + r;
                if (q == 0) {
                    ((float*)(smem + OFF_OUT4))[row * 4] = fmaxf(acc[r], 0.f);
                } else {
                    *(unsigned short*)(ACT + off128(row, 15 + q)) = f2bf(acc[r]);
                }
            }
        }
    }

    // ---- GEMM3: c1 = relu(cin @ Wc0^T)  [256,32]x[32,64], in-place over ACT ----
    {
        bf16x8 a3[4];
        #pragma unroll
        for (int m = 0; m < 4; ++m) a3[m] = ldf64(ACT, w * 64 + m * 16 + q, h8);
        asm volatile("s_waitcnt lgkmcnt(0)" ::: "memory");
        __builtin_amdgcn_sched_barrier(0);
        #pragma unroll
        for (int n = 0; n < 4; ++n) {
            bf16x8 b = ldf32(smem + OFF_WC0, n * 16 + q, h8);
            #pragma unroll
            for (int m = 0; m < 4; ++m) {
                f32x4 acc = {0.f, 0.f, 0.f, 0.f};
                acc = __builtin_amdgcn_mfma_f32_16x16x32_bf16(a3[m], b, acc, 0, 0, 0);
                #pragma unroll
                for (int r = 0; r < 4; ++r) {
                    int row = w * 64 + m * 16 + h4 + r;
                    *(unsigned short*)(ACT + off128(row, n * 16 + q)) = f2bf(fmaxf(acc[r], 0.f));
                }
            }
        }
    }

    // ---- GEMM4: c2 = relu(c1 @ Wc1^T)  [256,64]x[64,64], in-place ----
    {
        bf16x8 a4[4][2];
        #pragma unroll
        for (int m = 0; m < 4; ++m)
            #pragma unroll
            for (int kk = 0; kk < 2; ++kk)
                a4[m][kk] = ldf64(ACT, w * 64 + m * 16 + q, kk * 32 + h8);
        asm volatile("s_waitcnt lgkmcnt(0)" ::: "memory");
        __builtin_amdgcn_sched_barrier(0);
        #pragma unroll
        for (int n = 0; n < 4; ++n) {
            bf16x8 bA = ldf64(smem + OFF_WC1, n * 16 + q, h8);
            bf16x8 bB = ldf64(smem + OFF_WC1, n * 16 + q, 32 + h8);
            #pragma unroll
            for (int m = 0; m < 4; ++m) {
                f32x4 acc = {0.f, 0.f, 0.f, 0.f};
                acc = __builtin_amdgcn_mfma_f32_16x16x32_bf16(a4[m][0], bA, acc, 0, 0, 0);
                acc = __builtin_amdgcn_mfma_f32_16x16x32_bf16(a4[m][1], bB, acc, 0, 0, 0);
                #pragma unroll
                for (int r = 0; r < 4; ++r) {
                    int row = w * 64 + m * 16 + h4 + r;
                    *(unsigned short*)(ACT + off128(row, n * 16 + q)) = f2bf(fmaxf(acc[r], 0.f));
                }
            }
        }
    }

    // ---- GEMM5: colors = c2 @ Wc2^T (3 real rows) -> OUT4 cols 1..3 ----
    {
        bf16x8 a5[4][2];
        #pragma unroll
        for (int m = 0; m < 4; ++m)
            #pragma unroll
            for (int kk = 0; kk < 2; ++kk)
                a5[m][kk] = ldf64(ACT, w * 64 + m * 16 + q, kk * 32 + h8);
        #pragma unroll
        for (int m = 0; m < 4; ++m) {
            f32x4 acc = {0.f, 0.f, 0.f, 0.f};
            acc = __builtin_amdgcn_mfma_f32_16x16x32_bf16(a5[m][0], bW2[0], acc, 0, 0, 0);
            acc = __builtin_amdgcn_mfma_f32_16x16x32_bf16(a5[m][1], bW2[1], acc, 0, 0, 0);
            if (q < 3) {
                #pragma unroll
                for (int r = 0; r < 4; ++r) {
                    int row = w * 64 + m * 16 + h4 + r;
                    ((float*)(smem + OFF_OUT4))[row * 4 + 1 + q] = acc[r];
                }
            }
        }
    }

    __syncthreads();   // ---- barrier 2 ----

    // ---- output: thread writes its own 4 consecutive slots (64B contiguous) ----
    {
        const float4* o4 = (const float4*)(smem + OFF_OUT4);
        int ray = tid >> 7;
        float* op = out + ((size_t)b0 * 512 + tid * 4) * 4;
        int r = rank0;
        #pragma unroll
        for (int i = 0; i < 4; ++i) {
            float4 v = {0.f, 0.f, 0.f, 0.f};
            if (mb[i]) { v = o4[ray * 128 + r]; r++; }
            *(float4*)(op + i * 4) = v;
        }
    }
}

extern "C" void kernel_launch(void* const* d_in, const int* in_sizes, int n_in,
                              void* d_out, int out_size, void* d_ws, size_t ws_size,
                              hipStream_t stream) {
    const float* df   = (const float*)d_in[0];
    const void*  mk   = d_in[1];
    const float* rays = (const float*)d_in[2];
    const float* Ws0  = (const float*)d_in[3];
    const float* Ws1  = (const float*)d_in[4];
    const float* Wc0  = (const float*)d_in[5];
    const float* Wc1  = (const float*)d_in[6];
    const float* Wc2  = (const float*)d_in[7];
    float* out = (float*)d_out;
    int* flag = (int*)d_ws;

    int B = in_sizes[2] / 3;   // 8192 rays
    detect_mask_kernel<<<1, 64, 0, stream>>>((const int*)mk, flag);
    nnrender_main<<<B / 2, 256, 0, stream>>>(df, mk, rays, Ws0, Ws1, Wc0, Wc1, Wc2, out, flag);
}